// Round 20
// baseline (309.277 us; speedup 1.0000x reference)
//
#include <hip/hip_runtime.h>

typedef unsigned short u16;
typedef __attribute__((ext_vector_type(8))) short frag8;
typedef __attribute__((ext_vector_type(4))) float f32x4;

static constexpr int C = 768;
static constexpr int F3 = 2304;      // 3*C
static constexpr int MROWS = 32768;  // B*T*H*W
static constexpr float LNEPS = 1e-5f;

__device__ __forceinline__ float bfu2f(u16 u){
  union { unsigned u; float f; } x; x.u = (unsigned)u << 16; return x.f;
}
__device__ __forceinline__ u16 f2bfu(float f){
  union { float f; unsigned u; } x; x.f = f;
  unsigned r = x.u + 0x7fffu + ((x.u >> 16) & 1u);   // RNE bf16
  return (u16)(r >> 16);
}

__device__ __forceinline__ void gload16(const void* g, void* l){
  __builtin_amdgcn_global_load_lds(
      (const __attribute__((address_space(1))) void*)g,
      (__attribute__((address_space(3))) void*)l, 16, 0, 0);
}

// ---------------- fp32 -> bf16 weight conversion ----------------
__global__ __launch_bounds__(256) void cvt_bf16(const float* __restrict__ src,
                                                u16* __restrict__ dst, int n){
  int i = blockIdx.x * 256 + threadIdx.x;
  if (i < n) dst[i] = f2bfu(src[i]);
}

// ---------------- LN1: fp32 x -> bf16 y ----------------
__global__ __launch_bounds__(256) void ln1_kernel(const float* __restrict__ x,
    const float* __restrict__ w, const float* __restrict__ b, u16* __restrict__ y){
  const int lane = threadIdx.x & 63, wid = threadIdx.x >> 6;
  const size_t row = (size_t)blockIdx.x * 4 + wid;
  const float4* xr = reinterpret_cast<const float4*>(x + row * C);
  float v[12];
  #pragma unroll
  for (int j = 0; j < 3; j++){
    float4 t = xr[lane + j*64];
    v[j*4+0]=t.x; v[j*4+1]=t.y; v[j*4+2]=t.z; v[j*4+3]=t.w;
  }
  float s = 0.f, ss = 0.f;
  #pragma unroll
  for (int j = 0; j < 12; j++){ s += v[j]; ss += v[j]*v[j]; }
  #pragma unroll
  for (int o = 32; o; o >>= 1){ s += __shfl_xor(s, o, 64); ss += __shfl_xor(ss, o, 64); }
  const float mu = s * (1.f/768.f);
  const float rs = rsqrtf(ss*(1.f/768.f) - mu*mu + LNEPS);
  ushort4* yr = reinterpret_cast<ushort4*>(y + row * C);
  const float4* wv = reinterpret_cast<const float4*>(w);
  const float4* bv = reinterpret_cast<const float4*>(b);
  #pragma unroll
  for (int j = 0; j < 3; j++){
    float4 wj = wv[lane + j*64], bj = bv[lane + j*64];
    ushort4 o4;
    o4.x = f2bfu((v[j*4+0]-mu)*rs*wj.x + bj.x);
    o4.y = f2bfu((v[j*4+1]-mu)*rs*wj.y + bj.y);
    o4.z = f2bfu((v[j*4+2]-mu)*rs*wj.z + bj.z);
    o4.w = f2bfu((v[j*4+3]-mu)*rs*wj.w + bj.w);
    yr[lane + j*64] = o4;
  }
}

// ---------------- GEMM body (R20: ring-3, SINGLE barrier per K-tile) ----------------
// BM=128, BN=256, BK=32, 24 K-tiles, 256 thr / 4 waves, wave tile 128x64,
// 2 blocks/CU (72KB LDS). R12-R19 audit: per-tile 3536cy observed vs 2367
// serial {LDS 1125 + MFMA 1242} -> ~1100cy is barrier convoy with TWO
// barriers/tile. Ring R=3 with stage-lead L=2 satisfies R >= L+1, making the
// trailing barrier removable:
//   iter t: stage(t+2); vmcnt(6); reads(t); lgkm(0); MFMA(t); barrier.
// WAR: stage(t+2) writes buf[(t-1)%3]; its readers (iter t-1) drained lgkm
// BEFORE iter t-1's ending barrier, and stage(t+2) is issued after that
// barrier -> formally safe. RAW: vmcnt(6) at iter t retires stage(t+1)
// (issued 1 iter = ~3500cy ago, landed); iter t's ending barrier publishes it
// for iter t+1's reads; reads(t) covered by iter t-1's barrier. Wrapped tail
// (24->0, 25->1) keeps vmcnt uniform; slots match (24%3==0).
template<int MODE>
__device__ __forceinline__ void gemm_body(
    const u16* __restrict__ A, const u16* __restrict__ Bw,
    const float* __restrict__ bias, const float* __restrict__ resid,
    void* __restrict__ Cout, int Ndim, int K)
{
  __shared__ __align__(16) char lds[73728];     // ring-3 x (A 8KB + B 16KB)
  const int tid = threadIdx.x;
  const int lane = tid & 63, wn = tid >> 6;     // 4 waves, wave tile 128x64 at col wn*64
  const int ntn = Ndim >> 8;
  const int cpx = (int)gridDim.x >> 3;          // bijective XCD swizzle (grid%8==0)
  const int wg = ((int)blockIdx.x & 7) * cpx + ((int)blockIdx.x >> 3);
  const int bm = wg / ntn, bn = wg % ntn;
  const int m0 = bm << 7, n0 = bn << 8;

  const int rp = lane >> 2;
  const int rr = rp ^ ((rp >> 2) & 1);
  const int qq = (lane & 3) ^ (rr & 3);
  const u16* aS = A  + (size_t)(m0 + rr) * K + qq*8;
  const u16* bS = Bw + (size_t)(n0 + rr) * K + qq*8;
  const size_t rgK = 16 * (size_t)K;

  const int fr = lane & 15, kq = lane >> 4;
  const int sig16 = (((fr ^ ((fr >> 2) & 1)) << 2) | (kq ^ (fr & 3))) * 16;

  f32x4 acc[8][4] = {};   // [mf][nf], wave tile 128x64

  auto stage = [&](int ts){
    char* lb = lds + (ts % 3)*24576;
    const u16* a = aS + ts*32;
    const u16* b = bS + ts*32;
    gload16(a + (size_t)(2*wn    )*rgK, lb + (2*wn    )*1024);
    gload16(a + (size_t)(2*wn + 1)*rgK, lb + (2*wn + 1)*1024);
    #pragma unroll
    for (int i = 0; i < 4; i++)
      gload16(b + (size_t)(4*wn + i)*rgK, lb + 8192 + (4*wn + i)*1024);
  };

  // prologue: stage 0,1 in flight; retire stage(0); publish
  stage(0); stage(1);
  asm volatile("s_waitcnt vmcnt(6)" ::: "memory");
  __builtin_amdgcn_s_barrier();

  for (int t = 0; t < 24; ++t){
    int ts = t + 2; if (ts >= 24) ts -= 24;    // wrapped tail keeps vmcnt uniform
    stage(ts);                                  // outstanding: {t+1, t+2}
    asm volatile("s_waitcnt vmcnt(6)" ::: "memory");   // retire stage(t+1)

    const char* base = lds + (t % 3)*24576;
    const char* pb = base + 8192 + (wn*4)*1024 + sig16;
    frag8 af[8], bf[4];
    #pragma unroll
    for (int nf = 0; nf < 4; nf++) bf[nf] = *reinterpret_cast<const frag8*>(pb + nf*1024);
    #pragma unroll
    for (int mf = 0; mf < 8; mf++) af[mf] = *reinterpret_cast<const frag8*>(base + mf*1024 + sig16);
    asm volatile("s_waitcnt lgkmcnt(0)" ::: "memory");
    __builtin_amdgcn_sched_barrier(0);
    __builtin_amdgcn_s_setprio(1);
    #pragma unroll
    for (int mf = 0; mf < 8; mf++)
      #pragma unroll
      for (int nf = 0; nf < 4; nf++)
        acc[mf][nf] = __builtin_amdgcn_mfma_f32_16x16x32_bf16(bf[nf], af[mf], acc[mf][nf], 0, 0, 0);
    __builtin_amdgcn_s_setprio(0);
    __builtin_amdgcn_s_barrier();              // the ONLY barrier per K-tile
  }
  asm volatile("s_waitcnt vmcnt(0)" ::: "memory");   // drain wrapped tail stages

  const int em = fr, en = kq * 4;
  float4 bb[4];
  #pragma unroll
  for (int nf = 0; nf < 4; nf++)
    bb[nf] = *reinterpret_cast<const float4*>(bias + n0 + wn*64 + nf*16 + en);

  #pragma unroll
  for (int mf = 0; mf < 8; mf++){
    const size_t m = (size_t)(m0 + mf*16 + em);
    #pragma unroll
    for (int nf = 0; nf < 4; nf++){
      const int n = n0 + wn*64 + nf*16 + en;
      if (MODE == 0){
        ushort4 o4;
        o4.x = f2bfu(acc[mf][nf][0] + bb[nf].x);
        o4.y = f2bfu(acc[mf][nf][1] + bb[nf].y);
        o4.z = f2bfu(acc[mf][nf][2] + bb[nf].z);
        o4.w = f2bfu(acc[mf][nf][3] + bb[nf].w);
        *reinterpret_cast<ushort4*>((u16*)Cout + m * Ndim + n) = o4;
      } else {
        const float4 rr4 = *reinterpret_cast<const float4*>(resid + m * Ndim + n);
        float4 o4;
        o4.x = acc[mf][nf][0] + bb[nf].x + rr4.x;
        o4.y = acc[mf][nf][1] + bb[nf].y + rr4.y;
        o4.z = acc[mf][nf][2] + bb[nf].z + rr4.z;
        o4.w = acc[mf][nf][3] + bb[nf].w + rr4.w;
        *reinterpret_cast<float4*>((float*)Cout + m * Ndim + n) = o4;
      }
    }
  }
}

__global__ __launch_bounds__(256, 2) void gemm_qkv(
    const u16* __restrict__ A, const u16* __restrict__ Bw,
    const float* __restrict__ bias, void* __restrict__ Cout, int Ndim, int K){
  gemm_body<0>(A, Bw, bias, nullptr, Cout, Ndim, K);
}
__global__ __launch_bounds__(256, 2) void gemm_out(
    const u16* __restrict__ A, const u16* __restrict__ Bw,
    const float* __restrict__ bias, const float* __restrict__ resid,
    void* __restrict__ Cout, int Ndim, int K){
  gemm_body<1>(A, Bw, bias, resid, Cout, Ndim, K);
}

// ---------------- fused MFMA attention + LN2 (R17-exact, best measured) ----------------
__global__ __launch_bounds__(256, 3) void attn_ln2(const u16* __restrict__ qkv,
    const float* __restrict__ w2, const float* __restrict__ b2, u16* __restrict__ y2){
  __shared__ __align__(16) u16 Obuf[16][772];  // 24,704 B
  __shared__ __align__(16) u16 Vt[13864];      // 27,728 B; total 52,432 B
  const int tid = threadIdx.x;
  const int lane = tid & 63, wid = tid >> 6;
  const int bid = blockIdx.x;
  const int w = bid & 31, h = (bid >> 5) & 31, b = bid >> 10;
  const size_t rbase = (size_t)b*16384 + h*32 + w;     // + t*1024

  #pragma unroll
  for (int i = 0; i < 4; i++){
    const int idx = tid + i*256;
    if (idx < 786){
      int off;
      if (idx < 780){
        const int n = idx / 65, r = idx - n*65;
        off = (r < 64) ? (n*1154 + r*18 + 16) : (n*1154 + 1152);
      } else {
        off = 13848 + (idx - 780)*2;
      }
      *reinterpret_cast<unsigned*>(&Vt[off]) = 0u;
    }
  }

  #pragma unroll
  for (int it = 0; it < 6; it++){
    const int e = tid + it*256;
    const int t = e / 96, c = e % 96;
    const int n = c >> 3, j = c & 7;
    union { uint4 u; u16 s[8]; } vv;
    vv.u = *reinterpret_cast<const uint4*>(qkv + (rbase + (size_t)t*1024)*F3 + (n*24 + 16 + j)*8);
    #pragma unroll
    for (int x = 0; x < 8; x++)
      Vt[n*1154 + (j*8 + x)*18 + t] = vv.s[x];
  }
  __syncthreads();   // Vt (+pads) published

  const int q = lane >> 4, tcol = lane & 15;
  const u16* gq = qkv + (rbase + (size_t)tcol*1024)*F3;

  #pragma unroll
  for (int hh = 0; hh < 3; hh++){
    const int n = wid*3 + hh;
    const frag8 qf0 = *reinterpret_cast<const frag8*>(gq + (n*24 +  0 + q)*8);
    const frag8 qf1 = *reinterpret_cast<const frag8*>(gq + (n*24 +  4 + q)*8);
    const frag8 kf0 = *reinterpret_cast<const frag8*>(gq + (n*24 +  8 + q)*8);
    const frag8 kf1 = *reinterpret_cast<const frag8*>(gq + (n*24 + 12 + q)*8);
    f32x4 sa = {};
    sa = __builtin_amdgcn_mfma_f32_16x16x32_bf16(kf0, qf0, sa, 0, 0, 0);
    sa = __builtin_amdgcn_mfma_f32_16x16x32_bf16(kf1, qf1, sa, 0, 0, 0);
    const float sc0 = sa[0]*0.125f, sc1 = sa[1]*0.125f;
    const float sc2 = sa[2]*0.125f, sc3 = sa[3]*0.125f;
    float mx = fmaxf(fmaxf(sc0, sc1), fmaxf(sc2, sc3));
    mx = fmaxf(mx, __shfl_xor(mx, 16, 64));
    mx = fmaxf(mx, __shfl_xor(mx, 32, 64));
    float p0 = __expf(sc0-mx), p1 = __expf(sc1-mx), p2 = __expf(sc2-mx), p3 = __expf(sc3-mx);
    float sm = p0+p1+p2+p3;
    sm += __shfl_xor(sm, 16, 64);
    sm += __shfl_xor(sm, 32, 64);
    const float inv = 1.f / sm;
    const unsigned b0 = (unsigned)f2bfu(p0*inv) | ((unsigned)f2bfu(p1*inv) << 16);
    const unsigned b1 = (unsigned)f2bfu(p2*inv) | ((unsigned)f2bfu(p3*inv) << 16);
    const unsigned t0 = __shfl((unsigned)b0, (lane+16)&63, 64);
    const unsigned t1 = __shfl((unsigned)b1, (lane+16)&63, 64);
    const unsigned t2 = __shfl((unsigned)b0, (lane+32)&63, 64);
    const unsigned t3 = __shfl((unsigned)b1, (lane+32)&63, 64);
    union { frag8 f; unsigned u[4]; } pu;
    pu.u[0] = (q==0) ? b0 : ((q==1) ? t0 : 0u);
    pu.u[1] = (q==0) ? b1 : ((q==1) ? t1 : 0u);
    pu.u[2] = (q==0) ? t0 : ((q==1) ? t2 : 0u);
    pu.u[3] = (q==0) ? t1 : ((q==1) ? t3 : 0u);

    #pragma unroll
    for (int dcv = 0; dcv < 4; dcv++){
      union { frag8 f; unsigned u[4]; } vf;
      const int vi = n*1154 + (dcv*16 + tcol)*18 + q*8;
      #pragma unroll
      for (int i2 = 0; i2 < 4; i2++)
        vf.u[i2] = *reinterpret_cast<const unsigned*>(&Vt[vi + 2*i2]);
      f32x4 oa = {};
      oa = __builtin_amdgcn_mfma_f32_16x16x32_bf16(vf.f, pu.f, oa, 0, 0, 0);
      uint2 ow;
      ow.x = (unsigned)f2bfu(oa[0]) | ((unsigned)f2bfu(oa[1]) << 16);
      ow.y = (unsigned)f2bfu(oa[2]) | ((unsigned)f2bfu(oa[3]) << 16);
      *reinterpret_cast<uint2*>(&Obuf[tcol][n*64 + dcv*16 + q*4]) = ow;
    }
  }
  __syncthreads();

  #pragma unroll
  for (int rq = 0; rq < 4; rq++){
    const int t = wid*4 + rq;
    float v[12];
    #pragma unroll
    for (int j = 0; j < 12; j++) v[j] = bfu2f(Obuf[t][j*64 + lane]);
    float s = 0.f, ss = 0.f;
    #pragma unroll
    for (int j = 0; j < 12; j++){ s += v[j]; ss += v[j]*v[j]; }
    #pragma unroll
    for (int o = 32; o; o >>= 1){ s += __shfl_xor(s, o, 64); ss += __shfl_xor(ss, o, 64); }
    const float mu = s * (1.f/768.f);
    const float rs = rsqrtf(ss*(1.f/768.f) - mu*mu + LNEPS);
    u16* yr = y2 + (rbase + (size_t)t*1024) * C;
    #pragma unroll
    for (int j = 0; j < 12; j++){
      const int c = j*64 + lane;
      yr[c] = f2bfu((v[j]-mu)*rs*w2[c] + b2[c]);
    }
  }
}

extern "C" void kernel_launch(void* const* d_in, const int* in_sizes, int n_in,
                              void* d_out, int out_size, void* d_ws, size_t ws_size,
                              hipStream_t stream){
  const float* x    = (const float*)d_in[0];
  const float* ln1w = (const float*)d_in[1];
  const float* ln1b = (const float*)d_in[2];
  const float* Wqkv = (const float*)d_in[3];
  const float* bqkv = (const float*)d_in[4];
  const float* ln2w = (const float*)d_in[5];
  const float* ln2b = (const float*)d_in[6];
  const float* Wout = (const float*)d_in[7];
  const float* bout = (const float*)d_in[8];
  float* out = (float*)d_out;

  char* ws = (char*)d_ws;
  u16* qkv = (u16*)ws;                       // 32768*2304*2 = 150,994,944 B
  u16* y   = (u16*)(ws + 150994944);         // 32768*768*2  =  50,331,648 B (y1, then y2)
  u16* wq  = (u16*)(ws + 201326592);         // 2304*768*2   =   3,538,944 B
  u16* wo  = (u16*)(ws + 204865536);         // 768*768*2    =   1,179,648 B  (total 206,045,184)

  cvt_bf16<<<(F3*C + 255)/256, 256, 0, stream>>>(Wqkv, wq, F3*C);
  cvt_bf16<<<(C*C + 255)/256, 256, 0, stream>>>(Wout, wo, C*C);
  ln1_kernel<<<MROWS/4, 256, 0, stream>>>(x, ln1w, ln1b, y);
  gemm_qkv<<<(MROWS/128)*(F3/256), 256, 0, stream>>>(y, wq, bqkv, qkv, F3, C);
  attn_ln2<<<2*32*32, 256, 0, stream>>>(qkv, ln2w, ln2b, y);
  gemm_out<<<(MROWS/128)*(C/256), 256, 0, stream>>>(y, wo, bout, x, out, C, C);
}

// Round 22
// 309.096 us; speedup vs baseline: 1.0006x; 1.0006x over previous
//
#include <hip/hip_runtime.h>

typedef unsigned short u16;
typedef __attribute__((ext_vector_type(8))) short frag8;
typedef __attribute__((ext_vector_type(4))) float f32x4;

static constexpr int C = 768;
static constexpr int F3 = 2304;      // 3*C
static constexpr int MROWS = 32768;  // B*T*H*W
static constexpr float LNEPS = 1e-5f;

__device__ __forceinline__ float bfu2f(u16 u){
  union { unsigned u; float f; } x; x.u = (unsigned)u << 16; return x.f;
}
__device__ __forceinline__ u16 f2bfu(float f){
  union { float f; unsigned u; } x; x.f = f;
  unsigned r = x.u + 0x7fffu + ((x.u >> 16) & 1u);   // RNE bf16
  return (u16)(r >> 16);
}

__device__ __forceinline__ void gload16(const void* g, void* l){
  __builtin_amdgcn_global_load_lds(
      (const __attribute__((address_space(1))) void*)g,
      (__attribute__((address_space(3))) void*)l, 16, 0, 0);
}

// ---------------- fused fp32 -> bf16 weight conversion (both weights) ----------------
__global__ __launch_bounds__(256) void cvt_both(const float* __restrict__ wqkv,
    const float* __restrict__ wout, u16* __restrict__ dq, u16* __restrict__ dwo){
  const int i = blockIdx.x * 256 + threadIdx.x;
  if (i < F3*C) dq[i]  = f2bfu(wqkv[i]);
  if (i < C*C)  dwo[i] = f2bfu(wout[i]);
}

// ---------------- LN1: fp32 x -> bf16 y ----------------
__global__ __launch_bounds__(256) void ln1_kernel(const float* __restrict__ x,
    const float* __restrict__ w, const float* __restrict__ b, u16* __restrict__ y){
  const int lane = threadIdx.x & 63, wid = threadIdx.x >> 6;
  const size_t row = (size_t)blockIdx.x * 4 + wid;
  const float4* xr = reinterpret_cast<const float4*>(x + row * C);
  float v[12];
  #pragma unroll
  for (int j = 0; j < 3; j++){
    float4 t = xr[lane + j*64];
    v[j*4+0]=t.x; v[j*4+1]=t.y; v[j*4+2]=t.z; v[j*4+3]=t.w;
  }
  float s = 0.f, ss = 0.f;
  #pragma unroll
  for (int j = 0; j < 12; j++){ s += v[j]; ss += v[j]*v[j]; }
  #pragma unroll
  for (int o = 32; o; o >>= 1){ s += __shfl_xor(s, o, 64); ss += __shfl_xor(ss, o, 64); }
  const float mu = s * (1.f/768.f);
  const float rs = rsqrtf(ss*(1.f/768.f) - mu*mu + LNEPS);
  ushort4* yr = reinterpret_cast<ushort4*>(y + row * C);
  const float4* wv = reinterpret_cast<const float4*>(w);
  const float4* bv = reinterpret_cast<const float4*>(b);
  #pragma unroll
  for (int j = 0; j < 3; j++){
    float4 wj = wv[lane + j*64], bj = bv[lane + j*64];
    ushort4 o4;
    o4.x = f2bfu((v[j*4+0]-mu)*rs*wj.x + bj.x);
    o4.y = f2bfu((v[j*4+1]-mu)*rs*wj.y + bj.y);
    o4.z = f2bfu((v[j*4+2]-mu)*rs*wj.z + bj.z);
    o4.w = f2bfu((v[j*4+3]-mu)*rs*wj.w + bj.w);
    yr[lane + j*64] = o4;
  }
}

// ---------------- GEMM body (R22 = R21 intent: R16 skeleton, pins REMOVED) ----------------
// BM=128, BN=256, BK=32, 24 K-tiles, 256 thr / 4 waves, wave tile 128x64,
// 2 blocks/CU, dbuf-2 x 24KB. R12-R20 pinned {12 ds_read -> lgkm(0) ->
// sched_barrier(0) -> setprio(1) -> 32 MFMA}, forcing the LDS window and MFMA
// window strictly serial per wave (m141-style pessimization; m190: setprio
// negative on non-8-phase). R22 removes all three pins: the ds_reads are
// compiler-visible, so hipcc emits fine-grained lgkmcnt(N) letting the first
// MFMAs start while later reads are in flight (m97 behavior). Kept: vmcnt(6)
// before barrier (gload_lds deps are invisible to the compiler) + 2 barriers.
template<int MODE>
__device__ __forceinline__ void gemm_body(
    const u16* __restrict__ A, const u16* __restrict__ Bw,
    const float* __restrict__ bias, const float* __restrict__ resid,
    void* __restrict__ Cout, int Ndim, int K)
{
  __shared__ __align__(16) char lds[49152];     // dbuf-2 x (A 8KB + B 16KB)
  const int tid = threadIdx.x;
  const int lane = tid & 63, wn = tid >> 6;     // 4 waves, wave tile 128x64 at col wn*64
  const int ntn = Ndim >> 8;
  const int cpx = (int)gridDim.x >> 3;          // bijective XCD swizzle (grid%8==0)
  const int wg = ((int)blockIdx.x & 7) * cpx + ((int)blockIdx.x >> 3);
  const int bm = wg / ntn, bn = wg % ntn;
  const int m0 = bm << 7, n0 = bn << 8;

  const int rp = lane >> 2;
  const int rr = rp ^ ((rp >> 2) & 1);
  const int qq = (lane & 3) ^ (rr & 3);
  const u16* aS = A  + (size_t)(m0 + rr) * K + qq*8;
  const u16* bS = Bw + (size_t)(n0 + rr) * K + qq*8;
  const size_t rgK = 16 * (size_t)K;

  const int fr = lane & 15, kq = lane >> 4;
  const int sig16 = (((fr ^ ((fr >> 2) & 1)) << 2) | (kq ^ (fr & 3))) * 16;

  f32x4 acc[8][4] = {};   // [mf][nf], wave tile 128x64

  auto stage = [&](int ts){
    char* lb = lds + (ts & 1)*24576;
    const u16* a = aS + ts*32;
    const u16* b = bS + ts*32;
    gload16(a + (size_t)(2*wn    )*rgK, lb + (2*wn    )*1024);
    gload16(a + (size_t)(2*wn + 1)*rgK, lb + (2*wn + 1)*1024);
    #pragma unroll
    for (int i = 0; i < 4; i++)
      gload16(b + (size_t)(4*wn + i)*rgK, lb + 8192 + (4*wn + i)*1024);
  };

  stage(0);

  for (int t = 0; t < 24; ++t){
    int tn = t + 1; if (tn >= 24) tn = 0;
    stage(tn);
    asm volatile("s_waitcnt vmcnt(6)" ::: "memory");
    __builtin_amdgcn_s_barrier();

    const char* base = lds + (t & 1)*24576;
    const char* pb = base + 8192 + (wn*4)*1024 + sig16;
    frag8 af[8], bf[4];
    #pragma unroll
    for (int nf = 0; nf < 4; nf++) bf[nf] = *reinterpret_cast<const frag8*>(pb + nf*1024);
    #pragma unroll
    for (int mf = 0; mf < 8; mf++) af[mf] = *reinterpret_cast<const frag8*>(base + mf*1024 + sig16);
    // no lgkm(0)/sched_barrier/setprio: compiler emits fine-grained lgkmcnt(N)
    #pragma unroll
    for (int mf = 0; mf < 8; mf++)
      #pragma unroll
      for (int nf = 0; nf < 4; nf++)
        acc[mf][nf] = __builtin_amdgcn_mfma_f32_16x16x32_bf16(bf[nf], af[mf], acc[mf][nf], 0, 0, 0);
    __builtin_amdgcn_s_barrier();
  }
  asm volatile("s_waitcnt vmcnt(0)" ::: "memory");

  const int em = fr, en = kq * 4;
  float4 bb[4];
  #pragma unroll
  for (int nf = 0; nf < 4; nf++)
    bb[nf] = *reinterpret_cast<const float4*>(bias + n0 + wn*64 + nf*16 + en);

  #pragma unroll
  for (int mf = 0; mf < 8; mf++){
    const size_t m = (size_t)(m0 + mf*16 + em);
    #pragma unroll
    for (int nf = 0; nf < 4; nf++){
      const int n = n0 + wn*64 + nf*16 + en;
      if (MODE == 0){
        ushort4 o4;
        o4.x = f2bfu(acc[mf][nf][0] + bb[nf].x);
        o4.y = f2bfu(acc[mf][nf][1] + bb[nf].y);
        o4.z = f2bfu(acc[mf][nf][2] + bb[nf].z);
        o4.w = f2bfu(acc[mf][nf][3] + bb[nf].w);
        *reinterpret_cast<ushort4*>((u16*)Cout + m * Ndim + n) = o4;
      } else {
        const float4 rr4 = *reinterpret_cast<const float4*>(resid + m * Ndim + n);
        float4 o4;
        o4.x = acc[mf][nf][0] + bb[nf].x + rr4.x;
        o4.y = acc[mf][nf][1] + bb[nf].y + rr4.y;
        o4.z = acc[mf][nf][2] + bb[nf].z + rr4.z;
        o4.w = acc[mf][nf][3] + bb[nf].w + rr4.w;
        *reinterpret_cast<float4*>((float*)Cout + m * Ndim + n) = o4;
      }
    }
  }
}

__global__ __launch_bounds__(256, 2) void gemm_qkv(
    const u16* __restrict__ A, const u16* __restrict__ Bw,
    const float* __restrict__ bias, void* __restrict__ Cout, int Ndim, int K){
  gemm_body<0>(A, Bw, bias, nullptr, Cout, Ndim, K);
}
__global__ __launch_bounds__(256, 2) void gemm_out(
    const u16* __restrict__ A, const u16* __restrict__ Bw,
    const float* __restrict__ bias, const float* __restrict__ resid,
    void* __restrict__ Cout, int Ndim, int K){
  gemm_body<1>(A, Bw, bias, resid, Cout, Ndim, K);
}

// ---------------- fused MFMA attention + LN2 (R17-exact, best measured) ----------------
__global__ __launch_bounds__(256, 3) void attn_ln2(const u16* __restrict__ qkv,
    const float* __restrict__ w2, const float* __restrict__ b2, u16* __restrict__ y2){
  __shared__ __align__(16) u16 Obuf[16][772];  // 24,704 B
  __shared__ __align__(16) u16 Vt[13864];      // 27,728 B; total 52,432 B
  const int tid = threadIdx.x;
  const int lane = tid & 63, wid = tid >> 6;
  const int bid = blockIdx.x;
  const int w = bid & 31, h = (bid >> 5) & 31, b = bid >> 10;
  const size_t rbase = (size_t)b*16384 + h*32 + w;     // + t*1024

  #pragma unroll
  for (int i = 0; i < 4; i++){
    const int idx = tid + i*256;
    if (idx < 786){
      int off;
      if (idx < 780){
        const int n = idx / 65, r = idx - n*65;
        off = (r < 64) ? (n*1154 + r*18 + 16) : (n*1154 + 1152);
      } else {
        off = 13848 + (idx - 780)*2;
      }
      *reinterpret_cast<unsigned*>(&Vt[off]) = 0u;
    }
  }

  #pragma unroll
  for (int it = 0; it < 6; it++){
    const int e = tid + it*256;
    const int t = e / 96, c = e % 96;
    const int n = c >> 3, j = c & 7;
    union { uint4 u; u16 s[8]; } vv;
    vv.u = *reinterpret_cast<const uint4*>(qkv + (rbase + (size_t)t*1024)*F3 + (n*24 + 16 + j)*8);
    #pragma unroll
    for (int x = 0; x < 8; x++)
      Vt[n*1154 + (j*8 + x)*18 + t] = vv.s[x];
  }
  __syncthreads();   // Vt (+pads) published

  const int q = lane >> 4, tcol = lane & 15;
  const u16* gq = qkv + (rbase + (size_t)tcol*1024)*F3;

  #pragma unroll
  for (int hh = 0; hh < 3; hh++){
    const int n = wid*3 + hh;
    const frag8 qf0 = *reinterpret_cast<const frag8*>(gq + (n*24 +  0 + q)*8);
    const frag8 qf1 = *reinterpret_cast<const frag8*>(gq + (n*24 +  4 + q)*8);
    const frag8 kf0 = *reinterpret_cast<const frag8*>(gq + (n*24 +  8 + q)*8);
    const frag8 kf1 = *reinterpret_cast<const frag8*>(gq + (n*24 + 12 + q)*8);
    f32x4 sa = {};
    sa = __builtin_amdgcn_mfma_f32_16x16x32_bf16(kf0, qf0, sa, 0, 0, 0);
    sa = __builtin_amdgcn_mfma_f32_16x16x32_bf16(kf1, qf1, sa, 0, 0, 0);
    const float sc0 = sa[0]*0.125f, sc1 = sa[1]*0.125f;
    const float sc2 = sa[2]*0.125f, sc3 = sa[3]*0.125f;
    float mx = fmaxf(fmaxf(sc0, sc1), fmaxf(sc2, sc3));
    mx = fmaxf(mx, __shfl_xor(mx, 16, 64));
    mx = fmaxf(mx, __shfl_xor(mx, 32, 64));
    float p0 = __expf(sc0-mx), p1 = __expf(sc1-mx), p2 = __expf(sc2-mx), p3 = __expf(sc3-mx);
    float sm = p0+p1+p2+p3;
    sm += __shfl_xor(sm, 16, 64);
    sm += __shfl_xor(sm, 32, 64);
    const float inv = 1.f / sm;
    const unsigned b0 = (unsigned)f2bfu(p0*inv) | ((unsigned)f2bfu(p1*inv) << 16);
    const unsigned b1 = (unsigned)f2bfu(p2*inv) | ((unsigned)f2bfu(p3*inv) << 16);
    const unsigned t0 = __shfl((unsigned)b0, (lane+16)&63, 64);
    const unsigned t1 = __shfl((unsigned)b1, (lane+16)&63, 64);
    const unsigned t2 = __shfl((unsigned)b0, (lane+32)&63, 64);
    const unsigned t3 = __shfl((unsigned)b1, (lane+32)&63, 64);
    union { frag8 f; unsigned u[4]; } pu;
    pu.u[0] = (q==0) ? b0 : ((q==1) ? t0 : 0u);
    pu.u[1] = (q==0) ? b1 : ((q==1) ? t1 : 0u);
    pu.u[2] = (q==0) ? t0 : ((q==1) ? t2 : 0u);
    pu.u[3] = (q==0) ? t1 : ((q==1) ? t3 : 0u);

    #pragma unroll
    for (int dcv = 0; dcv < 4; dcv++){
      union { frag8 f; unsigned u[4]; } vf;
      const int vi = n*1154 + (dcv*16 + tcol)*18 + q*8;
      #pragma unroll
      for (int i2 = 0; i2 < 4; i2++)
        vf.u[i2] = *reinterpret_cast<const unsigned*>(&Vt[vi + 2*i2]);
      f32x4 oa = {};
      oa = __builtin_amdgcn_mfma_f32_16x16x32_bf16(vf.f, pu.f, oa, 0, 0, 0);
      uint2 ow;
      ow.x = (unsigned)f2bfu(oa[0]) | ((unsigned)f2bfu(oa[1]) << 16);
      ow.y = (unsigned)f2bfu(oa[2]) | ((unsigned)f2bfu(oa[3]) << 16);
      *reinterpret_cast<uint2*>(&Obuf[tcol][n*64 + dcv*16 + q*4]) = ow;
    }
  }
  __syncthreads();

  #pragma unroll
  for (int rq = 0; rq < 4; rq++){
    const int t = wid*4 + rq;
    float v[12];
    #pragma unroll
    for (int j = 0; j < 12; j++) v[j] = bfu2f(Obuf[t][j*64 + lane]);
    float s = 0.f, ss = 0.f;
    #pragma unroll
    for (int j = 0; j < 12; j++){ s += v[j]; ss += v[j]*v[j]; }
    #pragma unroll
    for (int o = 32; o; o >>= 1){ s += __shfl_xor(s, o, 64); ss += __shfl_xor(ss, o, 64); }
    const float mu = s * (1.f/768.f);
    const float rs = rsqrtf(ss*(1.f/768.f) - mu*mu + LNEPS);
    u16* yr = y2 + (rbase + (size_t)t*1024) * C;
    #pragma unroll
    for (int j = 0; j < 12; j++){
      const int c = j*64 + lane;
      yr[c] = f2bfu((v[j]-mu)*rs*w2[c] + b2[c]);
    }
  }
}

extern "C" void kernel_launch(void* const* d_in, const int* in_sizes, int n_in,
                              void* d_out, int out_size, void* d_ws, size_t ws_size,
                              hipStream_t stream){
  const float* x    = (const float*)d_in[0];
  const float* ln1w = (const float*)d_in[1];
  const float* ln1b = (const float*)d_in[2];
  const float* Wqkv = (const float*)d_in[3];
  const float* bqkv = (const float*)d_in[4];
  const float* ln2w = (const float*)d_in[5];
  const float* ln2b = (const float*)d_in[6];
  const float* Wout = (const float*)d_in[7];
  const float* bout = (const float*)d_in[8];
  float* out = (float*)d_out;

  char* ws = (char*)d_ws;
  u16* qkv = (u16*)ws;                       // 32768*2304*2 = 150,994,944 B
  u16* y   = (u16*)(ws + 150994944);         // 32768*768*2  =  50,331,648 B (y1, then y2)
  u16* wq  = (u16*)(ws + 201326592);         // 2304*768*2   =   3,538,944 B
  u16* wo  = (u16*)(ws + 204865536);         // 768*768*2    =   1,179,648 B  (total 206,045,184)

  cvt_both<<<(F3*C + 255)/256, 256, 0, stream>>>(Wqkv, Wout, wq, wo);
  ln1_kernel<<<MROWS/4, 256, 0, stream>>>(x, ln1w, ln1b, y);
  gemm_qkv<<<(MROWS/128)*(F3/256), 256, 0, stream>>>(y, wq, bqkv, qkv, F3, C);
  attn_ln2<<<2*32*32, 256, 0, stream>>>(qkv, ln2w, ln2b, y);
  gemm_out<<<(MROWS/128)*(C/256), 256, 0, stream>>>(y, wo, bout, x, out, C, C);
}

// Round 23
// 301.959 us; speedup vs baseline: 1.0242x; 1.0236x over previous
//
#include <hip/hip_runtime.h>

typedef unsigned short u16;
typedef __attribute__((ext_vector_type(8))) short frag8;
typedef __attribute__((ext_vector_type(4))) float f32x4;

static constexpr int C = 768;
static constexpr int F3 = 2304;      // 3*C
static constexpr int MROWS = 32768;  // B*T*H*W
static constexpr float LNEPS = 1e-5f;

__device__ __forceinline__ float bfu2f(u16 u){
  union { unsigned u; float f; } x; x.u = (unsigned)u << 16; return x.f;
}
__device__ __forceinline__ u16 f2bfu(float f){
  union { float f; unsigned u; } x; x.f = f;
  unsigned r = x.u + 0x7fffu + ((x.u >> 16) & 1u);   // RNE bf16
  return (u16)(r >> 16);
}

__device__ __forceinline__ void gload16(const void* g, void* l){
  __builtin_amdgcn_global_load_lds(
      (const __attribute__((address_space(1))) void*)g,
      (__attribute__((address_space(3))) void*)l, 16, 0, 0);
}

// ---------------- fused fp32 -> bf16 weight conversion (both weights) ----------------
__global__ __launch_bounds__(256) void cvt_both(const float* __restrict__ wqkv,
    const float* __restrict__ wout, u16* __restrict__ dq, u16* __restrict__ dwo){
  const int i = blockIdx.x * 256 + threadIdx.x;
  if (i < F3*C) dq[i]  = f2bfu(wqkv[i]);
  if (i < C*C)  dwo[i] = f2bfu(wout[i]);
}

// ---------------- LN1: fp32 x -> bf16 y ----------------
__global__ __launch_bounds__(256) void ln1_kernel(const float* __restrict__ x,
    const float* __restrict__ w, const float* __restrict__ b, u16* __restrict__ y){
  const int lane = threadIdx.x & 63, wid = threadIdx.x >> 6;
  const size_t row = (size_t)blockIdx.x * 4 + wid;
  const float4* xr = reinterpret_cast<const float4*>(x + row * C);
  float v[12];
  #pragma unroll
  for (int j = 0; j < 3; j++){
    float4 t = xr[lane + j*64];
    v[j*4+0]=t.x; v[j*4+1]=t.y; v[j*4+2]=t.z; v[j*4+3]=t.w;
  }
  float s = 0.f, ss = 0.f;
  #pragma unroll
  for (int j = 0; j < 12; j++){ s += v[j]; ss += v[j]*v[j]; }
  #pragma unroll
  for (int o = 32; o; o >>= 1){ s += __shfl_xor(s, o, 64); ss += __shfl_xor(ss, o, 64); }
  const float mu = s * (1.f/768.f);
  const float rs = rsqrtf(ss*(1.f/768.f) - mu*mu + LNEPS);
  ushort4* yr = reinterpret_cast<ushort4*>(y + row * C);
  const float4* wv = reinterpret_cast<const float4*>(w);
  const float4* bv = reinterpret_cast<const float4*>(b);
  #pragma unroll
  for (int j = 0; j < 3; j++){
    float4 wj = wv[lane + j*64], bj = bv[lane + j*64];
    ushort4 o4;
    o4.x = f2bfu((v[j*4+0]-mu)*rs*wj.x + bj.x);
    o4.y = f2bfu((v[j*4+1]-mu)*rs*wj.y + bj.y);
    o4.z = f2bfu((v[j*4+2]-mu)*rs*wj.z + bj.z);
    o4.w = f2bfu((v[j*4+3]-mu)*rs*wj.w + bj.w);
    yr[lane + j*64] = o4;
  }
}

// ---------------- GEMM body (R16/R17-exact: best-measured config, converged) ----------------
// BM=128, BN=256, BK=32, 24 K-tiles, 256 thr / 4 waves, wave tile 128x64,
// 2 blocks/CU, dbuf-2 x 24KB. Structure-family plateau: 12 variants (ring
// depth, barrier count, phases, frag dbuf, occupancy, tile shape, pins) all
// land 158-163us -> converged at ~730 TF for K=768.
template<int MODE>
__device__ __forceinline__ void gemm_body(
    const u16* __restrict__ A, const u16* __restrict__ Bw,
    const float* __restrict__ bias, const float* __restrict__ resid,
    void* __restrict__ Cout, int Ndim, int K)
{
  __shared__ __align__(16) char lds[49152];     // dbuf-2 x (A 8KB + B 16KB)
  const int tid = threadIdx.x;
  const int lane = tid & 63, wn = tid >> 6;     // 4 waves, wave tile 128x64 at col wn*64
  const int ntn = Ndim >> 8;
  const int cpx = (int)gridDim.x >> 3;          // bijective XCD swizzle (grid%8==0)
  const int wg = ((int)blockIdx.x & 7) * cpx + ((int)blockIdx.x >> 3);
  const int bm = wg / ntn, bn = wg % ntn;
  const int m0 = bm << 7, n0 = bn << 8;

  const int rp = lane >> 2;
  const int rr = rp ^ ((rp >> 2) & 1);
  const int qq = (lane & 3) ^ (rr & 3);
  const u16* aS = A  + (size_t)(m0 + rr) * K + qq*8;
  const u16* bS = Bw + (size_t)(n0 + rr) * K + qq*8;
  const size_t rgK = 16 * (size_t)K;

  const int fr = lane & 15, kq = lane >> 4;
  const int sig16 = (((fr ^ ((fr >> 2) & 1)) << 2) | (kq ^ (fr & 3))) * 16;

  f32x4 acc[8][4] = {};   // [mf][nf], wave tile 128x64

  auto stage = [&](int ts){
    char* lb = lds + (ts & 1)*24576;
    const u16* a = aS + ts*32;
    const u16* b = bS + ts*32;
    gload16(a + (size_t)(2*wn    )*rgK, lb + (2*wn    )*1024);
    gload16(a + (size_t)(2*wn + 1)*rgK, lb + (2*wn + 1)*1024);
    #pragma unroll
    for (int i = 0; i < 4; i++)
      gload16(b + (size_t)(4*wn + i)*rgK, lb + 8192 + (4*wn + i)*1024);
  };

  stage(0);

  for (int t = 0; t < 24; ++t){
    int tn = t + 1; if (tn >= 24) tn = 0;
    stage(tn);
    asm volatile("s_waitcnt vmcnt(6)" ::: "memory");
    __builtin_amdgcn_s_barrier();

    const char* base = lds + (t & 1)*24576;
    const char* pb = base + 8192 + (wn*4)*1024 + sig16;
    frag8 af[8], bf[4];
    #pragma unroll
    for (int nf = 0; nf < 4; nf++) bf[nf] = *reinterpret_cast<const frag8*>(pb + nf*1024);
    #pragma unroll
    for (int mf = 0; mf < 8; mf++) af[mf] = *reinterpret_cast<const frag8*>(base + mf*1024 + sig16);
    asm volatile("s_waitcnt lgkmcnt(0)" ::: "memory");
    __builtin_amdgcn_sched_barrier(0);
    __builtin_amdgcn_s_setprio(1);
    #pragma unroll
    for (int mf = 0; mf < 8; mf++)
      #pragma unroll
      for (int nf = 0; nf < 4; nf++)
        acc[mf][nf] = __builtin_amdgcn_mfma_f32_16x16x32_bf16(bf[nf], af[mf], acc[mf][nf], 0, 0, 0);
    __builtin_amdgcn_s_setprio(0);
    __builtin_amdgcn_s_barrier();
  }
  asm volatile("s_waitcnt vmcnt(0)" ::: "memory");

  const int em = fr, en = kq * 4;
  float4 bb[4];
  #pragma unroll
  for (int nf = 0; nf < 4; nf++)
    bb[nf] = *reinterpret_cast<const float4*>(bias + n0 + wn*64 + nf*16 + en);

  #pragma unroll
  for (int mf = 0; mf < 8; mf++){
    const size_t m = (size_t)(m0 + mf*16 + em);
    #pragma unroll
    for (int nf = 0; nf < 4; nf++){
      const int n = n0 + wn*64 + nf*16 + en;
      if (MODE == 0){
        ushort4 o4;
        o4.x = f2bfu(acc[mf][nf][0] + bb[nf].x);
        o4.y = f2bfu(acc[mf][nf][1] + bb[nf].y);
        o4.z = f2bfu(acc[mf][nf][2] + bb[nf].z);
        o4.w = f2bfu(acc[mf][nf][3] + bb[nf].w);
        *reinterpret_cast<ushort4*>((u16*)Cout + m * Ndim + n) = o4;
      } else {
        const float4 rr4 = *reinterpret_cast<const float4*>(resid + m * Ndim + n);
        float4 o4;
        o4.x = acc[mf][nf][0] + bb[nf].x + rr4.x;
        o4.y = acc[mf][nf][1] + bb[nf].y + rr4.y;
        o4.z = acc[mf][nf][2] + bb[nf].z + rr4.z;
        o4.w = acc[mf][nf][3] + bb[nf].w + rr4.w;
        *reinterpret_cast<float4*>((float*)Cout + m * Ndim + n) = o4;
      }
    }
  }
}

__global__ __launch_bounds__(256, 2) void gemm_qkv(
    const u16* __restrict__ A, const u16* __restrict__ Bw,
    const float* __restrict__ bias, void* __restrict__ Cout, int Ndim, int K){
  gemm_body<0>(A, Bw, bias, nullptr, Cout, Ndim, K);
}
__global__ __launch_bounds__(256, 2) void gemm_out(
    const u16* __restrict__ A, const u16* __restrict__ Bw,
    const float* __restrict__ bias, const float* __restrict__ resid,
    void* __restrict__ Cout, int Ndim, int K){
  gemm_body<1>(A, Bw, bias, resid, Cout, Ndim, K);
}

// ---------------- fused MFMA attention + LN2 (R17-exact, best measured) ----------------
__global__ __launch_bounds__(256, 3) void attn_ln2(const u16* __restrict__ qkv,
    const float* __restrict__ w2, const float* __restrict__ b2, u16* __restrict__ y2){
  __shared__ __align__(16) u16 Obuf[16][772];  // 24,704 B
  __shared__ __align__(16) u16 Vt[13864];      // 27,728 B; total 52,432 B
  const int tid = threadIdx.x;
  const int lane = tid & 63, wid = tid >> 6;
  const int bid = blockIdx.x;
  const int w = bid & 31, h = (bid >> 5) & 31, b = bid >> 10;
  const size_t rbase = (size_t)b*16384 + h*32 + w;     // + t*1024

  #pragma unroll
  for (int i = 0; i < 4; i++){
    const int idx = tid + i*256;
    if (idx < 786){
      int off;
      if (idx < 780){
        const int n = idx / 65, r = idx - n*65;
        off = (r < 64) ? (n*1154 + r*18 + 16) : (n*1154 + 1152);
      } else {
        off = 13848 + (idx - 780)*2;
      }
      *reinterpret_cast<unsigned*>(&Vt[off]) = 0u;
    }
  }

  #pragma unroll
  for (int it = 0; it < 6; it++){
    const int e = tid + it*256;
    const int t = e / 96, c = e % 96;
    const int n = c >> 3, j = c & 7;
    union { uint4 u; u16 s[8]; } vv;
    vv.u = *reinterpret_cast<const uint4*>(qkv + (rbase + (size_t)t*1024)*F3 + (n*24 + 16 + j)*8);
    #pragma unroll
    for (int x = 0; x < 8; x++)
      Vt[n*1154 + (j*8 + x)*18 + t] = vv.s[x];
  }
  __syncthreads();   // Vt (+pads) published

  const int q = lane >> 4, tcol = lane & 15;
  const u16* gq = qkv + (rbase + (size_t)tcol*1024)*F3;

  #pragma unroll
  for (int hh = 0; hh < 3; hh++){
    const int n = wid*3 + hh;
    const frag8 qf0 = *reinterpret_cast<const frag8*>(gq + (n*24 +  0 + q)*8);
    const frag8 qf1 = *reinterpret_cast<const frag8*>(gq + (n*24 +  4 + q)*8);
    const frag8 kf0 = *reinterpret_cast<const frag8*>(gq + (n*24 +  8 + q)*8);
    const frag8 kf1 = *reinterpret_cast<const frag8*>(gq + (n*24 + 12 + q)*8);
    f32x4 sa = {};
    sa = __builtin_amdgcn_mfma_f32_16x16x32_bf16(kf0, qf0, sa, 0, 0, 0);
    sa = __builtin_amdgcn_mfma_f32_16x16x32_bf16(kf1, qf1, sa, 0, 0, 0);
    const float sc0 = sa[0]*0.125f, sc1 = sa[1]*0.125f;
    const float sc2 = sa[2]*0.125f, sc3 = sa[3]*0.125f;
    float mx = fmaxf(fmaxf(sc0, sc1), fmaxf(sc2, sc3));
    mx = fmaxf(mx, __shfl_xor(mx, 16, 64));
    mx = fmaxf(mx, __shfl_xor(mx, 32, 64));
    float p0 = __expf(sc0-mx), p1 = __expf(sc1-mx), p2 = __expf(sc2-mx), p3 = __expf(sc3-mx);
    float sm = p0+p1+p2+p3;
    sm += __shfl_xor(sm, 16, 64);
    sm += __shfl_xor(sm, 32, 64);
    const float inv = 1.f / sm;
    const unsigned b0 = (unsigned)f2bfu(p0*inv) | ((unsigned)f2bfu(p1*inv) << 16);
    const unsigned b1 = (unsigned)f2bfu(p2*inv) | ((unsigned)f2bfu(p3*inv) << 16);
    const unsigned t0 = __shfl((unsigned)b0, (lane+16)&63, 64);
    const unsigned t1 = __shfl((unsigned)b1, (lane+16)&63, 64);
    const unsigned t2 = __shfl((unsigned)b0, (lane+32)&63, 64);
    const unsigned t3 = __shfl((unsigned)b1, (lane+32)&63, 64);
    union { frag8 f; unsigned u[4]; } pu;
    pu.u[0] = (q==0) ? b0 : ((q==1) ? t0 : 0u);
    pu.u[1] = (q==0) ? b1 : ((q==1) ? t1 : 0u);
    pu.u[2] = (q==0) ? t0 : ((q==1) ? t2 : 0u);
    pu.u[3] = (q==0) ? t1 : ((q==1) ? t3 : 0u);

    #pragma unroll
    for (int dcv = 0; dcv < 4; dcv++){
      union { frag8 f; unsigned u[4]; } vf;
      const int vi = n*1154 + (dcv*16 + tcol)*18 + q*8;
      #pragma unroll
      for (int i2 = 0; i2 < 4; i2++)
        vf.u[i2] = *reinterpret_cast<const unsigned*>(&Vt[vi + 2*i2]);
      f32x4 oa = {};
      oa = __builtin_amdgcn_mfma_f32_16x16x32_bf16(vf.f, pu.f, oa, 0, 0, 0);
      uint2 ow;
      ow.x = (unsigned)f2bfu(oa[0]) | ((unsigned)f2bfu(oa[1]) << 16);
      ow.y = (unsigned)f2bfu(oa[2]) | ((unsigned)f2bfu(oa[3]) << 16);
      *reinterpret_cast<uint2*>(&Obuf[tcol][n*64 + dcv*16 + q*4]) = ow;
    }
  }
  __syncthreads();

  #pragma unroll
  for (int rq = 0; rq < 4; rq++){
    const int t = wid*4 + rq;
    float v[12];
    #pragma unroll
    for (int j = 0; j < 12; j++) v[j] = bfu2f(Obuf[t][j*64 + lane]);
    float s = 0.f, ss = 0.f;
    #pragma unroll
    for (int j = 0; j < 12; j++){ s += v[j]; ss += v[j]*v[j]; }
    #pragma unroll
    for (int o = 32; o; o >>= 1){ s += __shfl_xor(s, o, 64); ss += __shfl_xor(ss, o, 64); }
    const float mu = s * (1.f/768.f);
    const float rs = rsqrtf(ss*(1.f/768.f) - mu*mu + LNEPS);
    u16* yr = y2 + (rbase + (size_t)t*1024) * C;
    #pragma unroll
    for (int j = 0; j < 12; j++){
      const int c = j*64 + lane;
      yr[c] = f2bfu((v[j]-mu)*rs*w2[c] + b2[c]);
    }
  }
}

extern "C" void kernel_launch(void* const* d_in, const int* in_sizes, int n_in,
                              void* d_out, int out_size, void* d_ws, size_t ws_size,
                              hipStream_t stream){
  const float* x    = (const float*)d_in[0];
  const float* ln1w = (const float*)d_in[1];
  const float* ln1b = (const float*)d_in[2];
  const float* Wqkv = (const float*)d_in[3];
  const float* bqkv = (const float*)d_in[4];
  const float* ln2w = (const float*)d_in[5];
  const float* ln2b = (const float*)d_in[6];
  const float* Wout = (const float*)d_in[7];
  const float* bout = (const float*)d_in[8];
  float* out = (float*)d_out;

  char* ws = (char*)d_ws;
  u16* qkv = (u16*)ws;                       // 32768*2304*2 = 150,994,944 B
  u16* y   = (u16*)(ws + 150994944);         // 32768*768*2  =  50,331,648 B (y1, then y2)
  u16* wq  = (u16*)(ws + 201326592);         // 2304*768*2   =   3,538,944 B
  u16* wo  = (u16*)(ws + 204865536);         // 768*768*2    =   1,179,648 B  (total 206,045,184)

  cvt_both<<<(F3*C + 255)/256, 256, 0, stream>>>(Wqkv, Wout, wq, wo);
  ln1_kernel<<<MROWS/4, 256, 0, stream>>>(x, ln1w, ln1b, y);
  gemm_qkv<<<(MROWS/128)*(F3/256), 256, 0, stream>>>(y, wq, bqkv, qkv, F3, C);
  attn_ln2<<<2*32*32, 256, 0, stream>>>(qkv, ln2w, ln2b, y);
  gemm_out<<<(MROWS/128)*(C/256), 256, 0, stream>>>(y, wo, bout, x, out, C, C);
}